// Round 21
// baseline (128.344 us; speedup 1.0000x reference)
//
#include <hip/hip_runtime.h>
#include <hip/hip_bf16.h>

typedef unsigned short bf16_t;
typedef __attribute__((ext_vector_type(8))) short bf16x8;
typedef __attribute__((ext_vector_type(4))) short bf16x4;
typedef __attribute__((ext_vector_type(4))) float f32x4;

#define MFMA16(a, b, c) __builtin_amdgcn_mfma_f32_16x16x32_bf16((a), (b), (c), 0, 0, 0)

__device__ __forceinline__ bf16_t f2bf(float f) {
  union { float f; unsigned u; } v; v.f = f;
  unsigned u = v.u;
  u += 0x7FFFu + ((u >> 16) & 1u);
  return (bf16_t)(u >> 16);
}

// packed fp32x2 -> bf16x2 (RNE), one VALU op
__device__ __forceinline__ unsigned cvt_pk_bf16(float lo, float hi) {
  unsigned r;
  asm volatile("v_cvt_pk_bf16_f32 %0, %1, %2" : "=v"(r) : "v"(lo), "v"(hi));
  return r;
}

__device__ __forceinline__ unsigned pack2(short lo, short hi) {
  return ((unsigned)(unsigned short)lo) | ((unsigned)(unsigned short)hi << 16);
}

__device__ __forceinline__ void gld_lds16(const void* g, void* l) {
  __builtin_amdgcn_global_load_lds(
      (const __attribute__((address_space(1))) unsigned int*)g,
      (__attribute__((address_space(3))) unsigned int*)l, 16, 0, 0);
}

// ---------------- elementwise fp32 -> bf16 (8/thread) ----------------
__global__ __launch_bounds__(256) void k_f32_to_bf16(const float* __restrict__ in,
                                                     bf16_t* __restrict__ out, int n8) {
  int i = blockIdx.x * 256 + threadIdx.x;
  if (i >= n8) return;
  const float4* p = (const float4*)in + (size_t)i * 2;
  float4 a = p[0], b = p[1];
  bf16x8 o;
  o[0] = (short)f2bf(a.x); o[1] = (short)f2bf(a.y); o[2] = (short)f2bf(a.z); o[3] = (short)f2bf(a.w);
  o[4] = (short)f2bf(b.x); o[5] = (short)f2bf(b.y); o[6] = (short)f2bf(b.z); o[7] = (short)f2bf(b.w);
  *((bf16x8*)out + i) = o;
}

// ---------------- transpose + convert: W[K][N] f32 -> Wt[N][K] bf16 ----------------
__global__ __launch_bounds__(256) void k_transpose_bf16(const float* __restrict__ W,
                                                        bf16_t* __restrict__ Wt, int K, int N) {
  __shared__ bf16_t t[64][65];
  int n0 = blockIdx.x * 64, k0 = blockIdx.y * 64;
  int tid = threadIdx.x;
#pragma unroll
  for (int p = 0; p < 16; ++p) {
    int lin = p * 256 + tid;
    int r = lin >> 6, c = lin & 63;
    t[r][c] = f2bf(W[(size_t)(k0 + r) * N + n0 + c]);
  }
  __syncthreads();
#pragma unroll
  for (int p = 0; p < 16; ++p) {
    int lin = p * 256 + tid;
    int nr = lin >> 6, kc = lin & 63;
    Wt[(size_t)(n0 + nr) * K + k0 + kc] = t[kc][nr];
  }
}

// ---------------- GEMM-BT, depth-1 async pipeline ----------------
// R21: QKV moves to the proj-style config (BM=128, BN=64, TPB=256, 6 blocks/CU).
// Measured motivation: proj (4-wave blocks, 4/CU) runs ~860 TF vs QKV's ~630 at
// identical code/K — smaller barrier groups + more independent blocks per CU give
// finer-grained cross-block overlap (m114). B re-read multiplicity = M/BM is
// unchanged (R15 lesson respected); only A (8MB, 256KB panels) is re-read more.
template <bool BF16OUT, bool SCALEQ, int BM, int BN, int TPB>
__global__ __launch_bounds__(TPB) void k_gemm_bt(const bf16_t* __restrict__ A,
                                                 const bf16_t* __restrict__ Bt,
                                                 const float* __restrict__ bias,
                                                 void* __restrict__ Cout, int M, int N, int K,
                                                 int nx) {
  constexpr int WN = (TPB == 512) ? 4 : 2;   // waves along N
  constexpr int WM = (TPB / 64) / WN;        // waves along M (=2)
  constexpr int WTM = BM / WM;               // wave tile rows
  constexpr int WTN = BN / WN;               // wave tile cols
  constexpr int NI = WTM / 16;
  constexpr int NJ = WTN / 16;
  constexpr int PA = BM * 4 / TPB;           // A staging passes (16B/thread each)
  constexpr int PB = BN * 4 / TPB;
  __shared__ bf16_t Al[2][BM * 32];
  __shared__ bf16_t Bl[2][BN * 32];
  const int tid = threadIdx.x;
  const int lane = tid & 63;
  const int wid = tid >> 6;
  const int wm = wid / WN, wn = wid % WN;
  const int nwg = gridDim.x;
  const int cpx = nwg >> 3;
  const int swz = (blockIdx.x & 7) * cpx + (blockIdx.x >> 3);
  const int m0 = (swz / nx) * BM, n0 = (swz % nx) * BN;
  const int lr = lane & 15;
  const int lk = lane >> 4;

  f32x4 acc[NI][NJ] = {};

  auto STAGE = [&](int buf, int k0) {
#pragma unroll
    for (int p = 0; p < PA; ++p) {
      int o = p * TPB * 16 + tid * 16;
      int row = o >> 6, cb = o & 63;
      gld_lds16((const char*)A + ((size_t)(m0 + row) * K + k0) * 2 + cb,
                (char*)Al[buf] + o);
    }
#pragma unroll
    for (int p = 0; p < PB; ++p) {
      int o = p * TPB * 16 + tid * 16;
      int row = o >> 6, cb = o & 63;
      gld_lds16((const char*)Bt + ((size_t)(n0 + row) * K + k0) * 2 + cb,
                (char*)Bl[buf] + o);
    }
  };

  // prologue: issue stage(0); the loop's first vmcnt(0)+barrier completes it
  STAGE(0, 0);

  const int nk = K >> 5;
  for (int t = 0; t < nk; ++t) {
    const int cur = t & 1;
    // drain stage(t) (issued last iter; nothing newer in flight), then rendezvous
    asm volatile("s_waitcnt vmcnt(0)" ::: "memory");
    __builtin_amdgcn_s_barrier();
    // issue stage(t+1) now — hides under this iteration's compute
    if (t + 1 < nk) STAGE(cur ^ 1, (t + 1) << 5);
    bf16x8 af[NI], bfr[NJ];
#pragma unroll
    for (int i = 0; i < NI; ++i)
      af[i] = *(const bf16x8*)(Al[cur] + ((wm * WTM + i * 16 + lr) * 32 + lk * 8));
#pragma unroll
    for (int j = 0; j < NJ; ++j)
      bfr[j] = *(const bf16x8*)(Bl[cur] + ((wn * WTN + j * 16 + lr) * 32 + lk * 8));
#pragma unroll
    for (int i = 0; i < NI; ++i)
#pragma unroll
      for (int j = 0; j < NJ; ++j)
        acc[i][j] = MFMA16(af[i], bfr[j], acc[i][j]);
  }

#pragma unroll
  for (int i = 0; i < NI; ++i) {
    int grow = m0 + wm * WTM + i * 16 + lk * 4;
#pragma unroll
    for (int j = 0; j < NJ; ++j) {
      int gcol = n0 + wn * WTN + j * 16 + lr;
      float bv = bias[gcol];
      float scl = (SCALEQ && gcol < 1024) ? 0.18033688011112042f : 1.0f;
#pragma unroll
      for (int r = 0; r < 4; ++r) {
        float v = (acc[i][j][r] + bv) * scl;
        size_t off = (size_t)(grow + r) * N + gcol;
        if (BF16OUT)
          ((bf16_t*)Cout)[off] = f2bf(v);
        else
          ((float*)Cout)[off] = v;
      }
    }
  }
}

// ---------------- fused causal attention (swapped QK^T, K via LDS, static softmax) ----------------
// Parked (latency-chain-bound at ~50us). 1024 blocks, one q-tile each (balanced-
// quartet qt mapping); 4 waves x 16 q-rows; K staged once/block via global_load_lds
// (double-buffered, inverse-swizzled source + T2-swizzled b128 reads); Vt double-
// buffered via reg ping-pong (one raw barrier/step); counted vmcnt; swapped MFMAs;
// static softmax (no max subtraction; |s| <~ 6 bounded); packed epilogue.
__global__ __launch_bounds__(256) void k_attn(const bf16_t* __restrict__ qkv,
                                              bf16_t* __restrict__ score) {
  __shared__ bf16_t Kl[2][64 * 64];  // [buf][kv-row][chunk'] 16 KiB, swizzled chunks
  __shared__ bf16_t Vt[2][64 * 64];  // [buf][d][kv] swizzled, 16 KiB
  __shared__ bf16_t Pl[4][16 * 64];  // per-wave P [q][kv] swizzled, 8 KiB
  const int tid = threadIdx.x;
  const int lane = tid & 63;
  const int w = tid >> 6;
  const int lr = lane & 15, lk = lane >> 4;

  const int flat = blockIdx.x;
  const int g = flat >> 5;
  const int idx = g & 7;
  const int grp = g >> 3;
  const int qt = (grp == 0) ? (31 - idx)
               : (grp == 1) ? (15 - idx)
               : (grp == 2) ? (16 + idx)
                            : idx;  // balanced quartets
  const int bh = flat & 31;
  const int b = bh >> 4, h = bh & 15;

  const bf16_t* Qb = qkv + (size_t)b * 2048 * 3072 + h * 64;
  const bf16_t* Kb = Qb + 1024;
  const bf16_t* Vb = Qb + 2048;

  // V staging coords: pass p, thread t: e=p*256+t; d0=(e&15)*4 (4 d's), kv=2*(e>>4)
  // K staging coords: thread t2 stages global chunk (t2&7)^(row&7) of row t2>>3
  int d0c[2], kv2[2], krow[2], kchk[2];
#pragma unroll
  for (int p = 0; p < 2; ++p) {
    int e = p * 256 + tid;
    d0c[p] = (e & 15) * 4;
    kv2[p] = (e >> 4) * 2;
    krow[p] = e >> 3;
    kchk[p] = (e & 7) ^ (krow[p] & 7);
  }

  const int qr0 = qt * 64 + w * 16;
  const int q = qr0 + lr;  // this lane's q-row (swapped layout)
  const int jtEnd = qt + 1;

  // hoist Q fragments (pre-scaled by 1/sqrt(64)*log2e in the GEMM)
  bf16x8 qf[2];
#pragma unroll
  for (int ks = 0; ks < 2; ++ks)
    qf[ks] = *(const bf16x8*)(Qb + (size_t)(qr0 + lr) * 3072 + ks * 32 + lk * 8);

  f32x4 o[4] = {};
  float l = 0.f;

  // prologue: V(0)->Vt buf0 via regs (paired-kv b32 writes)
  {
    bf16x4 v0[2][2];
#pragma unroll
    for (int p = 0; p < 2; ++p) {
      v0[p][0] = *(const bf16x4*)(Vb + (size_t)kv2[p] * 3072 + d0c[p]);
      v0[p][1] = *(const bf16x4*)(Vb + (size_t)(kv2[p] + 1) * 3072 + d0c[p]);
    }
#pragma unroll
    for (int p = 0; p < 2; ++p)
#pragma unroll
      for (int j = 0; j < 4; ++j) {
        int d = d0c[p] + j;
        int addr = (d * 128 + kv2[p] * 2) ^ (((d & 7) ^ ((d >> 3) & 7)) << 4);
        *(unsigned*)((char*)Vt + addr) = pack2(v0[p][0][j], v0[p][1][j]);
      }
  }
  // prefetch V(1) regs, then issue K(0) gld_lds (order matters for vmcnt counts)
  bf16x4 vrA[2][2], vrB[2][2];
#pragma unroll
  for (int p = 0; p < 2; ++p) {
    vrA[p][0] = *(const bf16x4*)(Vb + (size_t)(64 + kv2[p]) * 3072 + d0c[p]);
    vrA[p][1] = *(const bf16x4*)(Vb + (size_t)(64 + kv2[p] + 1) * 3072 + d0c[p]);
  }
#pragma unroll
  for (int p = 0; p < 2; ++p)
    gld_lds16((const char*)Kb + ((size_t)krow[p] * 3072 + kchk[p] * 8) * 2,
              (char*)Kl + (p * 256 + tid) * 16);

  auto STEP = [&](int jt, bf16x4 (&vrC)[2][2], bf16x4 (&vrN)[2][2], bool last) {
    const int kv0 = jt * 64;
    // one barrier/step: prev-step LDS traffic drained (lgkm only; vmem in flight)
    asm volatile("s_waitcnt lgkmcnt(0)" ::: "memory");
    __builtin_amdgcn_s_barrier();
    // write V(jt+1) from regs into Vt buf[(jt+1)&1]: paired-kv b32
    char* wbase = (char*)Vt + (((jt + 1) & 1) << 13);
#pragma unroll
    for (int p = 0; p < 2; ++p)
#pragma unroll
      for (int j = 0; j < 4; ++j) {
        int d = d0c[p] + j;
        int addr = (d * 128 + kv2[p] * 2) ^ (((d & 7) ^ ((d >> 3) & 7)) << 4);
        *(unsigned*)(wbase + addr) = pack2(vrC[p][0][j], vrC[p][1][j]);
      }
    if (!last) {
      // prefetch V(jt+2) regs (4 loads), then K(jt+1) -> Kl buf[(jt+1)&1]
      const int kvV = (kv0 + 128 < 2048) ? kv0 + 128 : 1920;
#pragma unroll
      for (int p = 0; p < 2; ++p) {
        vrN[p][0] = *(const bf16x4*)(Vb + (size_t)(kvV + kv2[p]) * 3072 + d0c[p]);
        vrN[p][1] = *(const bf16x4*)(Vb + (size_t)(kvV + kv2[p] + 1) * 3072 + d0c[p]);
      }
      char* kbase = (char*)Kl + (((jt + 1) & 1) << 13);
#pragma unroll
      for (int p = 0; p < 2; ++p)
        gld_lds16((const char*)Kb + ((size_t)(kv0 + 64 + krow[p]) * 3072 + kchk[p] * 8) * 2,
                  kbase + (p * 256 + tid) * 16);
      // drain this step's K (2 oldest); keep 4 V + 2 K just issued in flight
      asm volatile("s_waitcnt vmcnt(6)" ::: "memory");
    } else {
      asm volatile("s_waitcnt vmcnt(0)" ::: "memory");
    }
    // K fragments from swizzled LDS buf[jt&1]
    const char* kread = (const char*)Kl + ((jt & 1) << 13);
    bf16x8 kf[4][2];
#pragma unroll
    for (int nc = 0; nc < 4; ++nc) {
      const char* rowp = kread + (nc * 16 + lr) * 128;
      kf[nc][0] = *(const bf16x8*)(rowp + ((lk ^ (lr & 7)) << 4));
      kf[nc][1] = *(const bf16x8*)(rowp + (((4 | lk) ^ (lr & 7)) << 4));
    }
    // S^T = K Q^T (swapped): s[nc][r] is (q=qr0+lr, kv=kv0+nc*16+lk*4+r)
    f32x4 s[4];
    __builtin_amdgcn_s_setprio(1);
#pragma unroll
    for (int nc = 0; nc < 4; ++nc) {
      f32x4 z = {};
      z = MFMA16(kf[nc][0], qf[0], z);
      z = MFMA16(kf[nc][1], qf[1], z);
      s[nc] = z;
    }
    __builtin_amdgcn_s_setprio(0);
    // causal mask (last tile of this wave only); exp2(-inf) = 0 below
    if (kv0 + 63 > qr0) {
#pragma unroll
      for (int nc = 0; nc < 4; ++nc)
#pragma unroll
        for (int r = 0; r < 4; ++r) {
          int kvi = kv0 + nc * 16 + lk * 4 + r;
          if (kvi > q) s[nc][r] = -INFINITY;
        }
    }
    // static softmax (base-2, no max subtraction); per-lane partial l
#pragma unroll
    for (int nc = 0; nc < 4; ++nc)
#pragma unroll
      for (int r = 0; r < 4; ++r) {
        float p = exp2f(s[nc][r]);
        s[nc][r] = p;
        l += p;
      }
    // P -> per-wave LDS: cvt_pk pairs packed into b64 writes
    bf16_t* Pw = Pl[w];
#pragma unroll
    for (int nc = 0; nc < 4; ++nc) {
      uint2 u;
      u.x = cvt_pk_bf16(s[nc][0], s[nc][1]);
      u.y = cvt_pk_bf16(s[nc][2], s[nc][3]);
      int addr = (lr * 128 + (nc * 16 + lk * 4) * 2) ^ ((lr & 7) << 4);
      *(uint2*)((char*)Pw + addr) = u;
    }
    // PV (swapped): o[db] += mfma(V^T-frag, P-frag) -> O^T (row=d, col=q)
    const char* rbase = (const char*)Vt + ((jt & 1) << 13);
    bf16x8 pa[2];
#pragma unroll
    for (int ks = 0; ks < 2; ++ks) {
      int addr = (lr * 128 + ks * 64 + lk * 16) ^ ((lr & 7) << 4);
      pa[ks] = *(const bf16x8*)((const char*)Pl[w] + addr);
    }
    __builtin_amdgcn_s_setprio(1);
#pragma unroll
    for (int db = 0; db < 4; ++db)
#pragma unroll
      for (int ks = 0; ks < 2; ++ks) {
        int d = db * 16 + lr;
        int addr = (d * 128 + ks * 64 + lk * 16) ^ (((d & 7) ^ ((d >> 3) & 7)) << 4);
        bf16x8 vb = *(const bf16x8*)(rbase + addr);
        o[db] = MFMA16(vb, pa[ks], o[db]);
      }
    __builtin_amdgcn_s_setprio(0);
  };

  int jt = 0;
  for (;;) {
    STEP(jt, vrA, vrB, jt + 1 == jtEnd);
    if (++jt == jtEnd) break;
    STEP(jt, vrB, vrA, jt + 1 == jtEnd);
    if (++jt == jtEnd) break;
  }

  // epilogue: cross-lane sum of l (lanes lr, lr+16, lr+32, lr+48 share q-row);
  // lane writes its q-row, d = db*16 + lk*4 + r (packed 8B stores)
  l += __shfl_xor(l, 16);
  l += __shfl_xor(l, 32);
  const float rl = 1.0f / l;
  bf16_t* orow = score + (size_t)(b * 2048 + q) * 1024 + h * 64 + lk * 4;
#pragma unroll
  for (int db = 0; db < 4; ++db) {
    unsigned w0 = cvt_pk_bf16(o[db][0] * rl, o[db][1] * rl);
    unsigned w1 = cvt_pk_bf16(o[db][2] * rl, o[db][3] * rl);
    uint2 pkt; pkt.x = w0; pkt.y = w1;
    *(uint2*)(orow + db * 16) = pkt;
  }
}

extern "C" void kernel_launch(void* const* d_in, const int* in_sizes, int n_in,
                              void* d_out, int out_size, void* d_ws, size_t ws_size,
                              hipStream_t stream) {
  const float* X  = (const float*)d_in[0];  // [2,2048,1024]
  const float* Wa = (const float*)d_in[1];  // [1024,3072]
  const float* ba = (const float*)d_in[2];  // [3072]
  const float* Wp = (const float*)d_in[3];  // [1024,1024]
  const float* bp = (const float*)d_in[4];  // [1024]
  float* out = (float*)d_out;               // [2,2048,1024] fp32

  char* ws = (char*)d_ws;
  bf16_t* Xb  = (bf16_t*)ws;                          // 8 MiB (reused as score)
  bf16_t* WaT = (bf16_t*)(ws + (size_t)(8u << 20));   // 6 MiB: W_attn^T [3072][1024]
  bf16_t* WpT = (bf16_t*)(ws + (size_t)(14u << 20));  // 2 MiB: W_proj^T [1024][1024]
  bf16_t* QKV = (bf16_t*)(ws + (size_t)(16u << 20));  // 24 MiB: [4096][3072]
  bf16_t* S_  = Xb;

  k_f32_to_bf16<<<2048, 256, 0, stream>>>(X, Xb, 4096 * 1024 / 8);
  k_transpose_bf16<<<dim3(48, 16), 256, 0, stream>>>(Wa, WaT, 1024, 3072);
  k_transpose_bf16<<<dim3(16, 16), 256, 0, stream>>>(Wp, WpT, 1024, 1024);
  // QKV: 128x64 tile, 256 threads (proj-style) -> 32*48 = 1536 blocks = 6/CU
  k_gemm_bt<true, true, 128, 64, 256><<<1536, 256, 0, stream>>>(Xb, WaT, ba, QKV, 4096, 3072, 1024, 48);
  k_attn<<<1024, 256, 0, stream>>>(QKV, S_);
  // proj: 64x64 tile, 256 threads -> 1024 blocks = 4/CU
  k_gemm_bt<false, false, 64, 64, 256><<<1024, 256, 0, stream>>>(S_, WpT, bp, out, 4096, 1024, 1024, 16);
}

// Round 22
// 108.375 us; speedup vs baseline: 1.1843x; 1.1843x over previous
//
#include <hip/hip_runtime.h>
#include <hip/hip_bf16.h>

typedef unsigned short bf16_t;
typedef __attribute__((ext_vector_type(8))) short bf16x8;
typedef __attribute__((ext_vector_type(4))) short bf16x4;
typedef __attribute__((ext_vector_type(4))) float f32x4;

#define MFMA16(a, b, c) __builtin_amdgcn_mfma_f32_16x16x32_bf16((a), (b), (c), 0, 0, 0)

__device__ __forceinline__ bf16_t f2bf(float f) {
  union { float f; unsigned u; } v; v.f = f;
  unsigned u = v.u;
  u += 0x7FFFu + ((u >> 16) & 1u);
  return (bf16_t)(u >> 16);
}

// packed fp32x2 -> bf16x2 (RNE), one VALU op
__device__ __forceinline__ unsigned cvt_pk_bf16(float lo, float hi) {
  unsigned r;
  asm volatile("v_cvt_pk_bf16_f32 %0, %1, %2" : "=v"(r) : "v"(lo), "v"(hi));
  return r;
}

__device__ __forceinline__ unsigned pack2(short lo, short hi) {
  return ((unsigned)(unsigned short)lo) | ((unsigned)(unsigned short)hi << 16);
}

__device__ __forceinline__ void gld_lds16(const void* g, void* l) {
  __builtin_amdgcn_global_load_lds(
      (const __attribute__((address_space(1))) unsigned int*)g,
      (__attribute__((address_space(3))) unsigned int*)l, 16, 0, 0);
}

// ---------------- fused prep: X f32->bf16 + transpose both weights ----------------
// R22: one launch replaces three (saves launch gaps + small-grid tails).
// blocks [0,2048): convert X (8 elems/thread).
// blocks [2048,2816): transpose W_attn [1024][3072] -> WaT [3072][1024].
// blocks [2816,3072): transpose W_proj [1024][1024] -> WpT [1024][1024].
__global__ __launch_bounds__(256) void k_prep(const float* __restrict__ X,
                                              bf16_t* __restrict__ Xb,
                                              const float* __restrict__ Wa,
                                              bf16_t* __restrict__ WaT,
                                              const float* __restrict__ Wp,
                                              bf16_t* __restrict__ WpT) {
  __shared__ bf16_t t[64][65];
  const int blk = blockIdx.x;
  const int tid = threadIdx.x;
  if (blk < 2048) {
    int i = blk * 256 + tid;
    const float4* p = (const float4*)X + (size_t)i * 2;
    float4 a = p[0], b = p[1];
    bf16x8 o;
    o[0] = (short)f2bf(a.x); o[1] = (short)f2bf(a.y); o[2] = (short)f2bf(a.z); o[3] = (short)f2bf(a.w);
    o[4] = (short)f2bf(b.x); o[5] = (short)f2bf(b.y); o[6] = (short)f2bf(b.z); o[7] = (short)f2bf(b.w);
    *((bf16x8*)Xb + i) = o;
    return;
  }
  const bool wa = (blk < 2816);
  const int bx = wa ? (blk - 2048) : (blk - 2816);
  const int NX = wa ? 48 : 16;                    // N/64
  const int N = wa ? 3072 : 1024;
  const int K = 1024;
  const float* W = wa ? Wa : Wp;
  bf16_t* Wt = wa ? WaT : WpT;
  const int n0 = (bx % NX) * 64, k0 = (bx / NX) * 64;
#pragma unroll
  for (int p = 0; p < 16; ++p) {
    int lin = p * 256 + tid;
    int r = lin >> 6, c = lin & 63;
    t[r][c] = f2bf(W[(size_t)(k0 + r) * N + n0 + c]);
  }
  __syncthreads();
#pragma unroll
  for (int p = 0; p < 16; ++p) {
    int lin = p * 256 + tid;
    int nr = lin >> 6, kc = lin & 63;
    Wt[(size_t)(n0 + nr) * K + k0 + kc] = t[kc][nr];
  }
}

// ---------------- GEMM-BT, depth-1 async pipeline ----------------
// Best-measured configs (R15/R21 lesson: 768 blocks @128x128 is the L2-optimal
// point for QKV — both 64-row and 64-col shrinks blew FETCH 28->46-54MB).
// Depth-1 order: {vmcnt(0) [drains stage(t) from last iter]; s_barrier;
// STAGE(t+1); compute(t)} — stage hides under the whole iteration.
template <bool BF16OUT, bool SCALEQ, int BM, int BN, int TPB>
__global__ __launch_bounds__(TPB) void k_gemm_bt(const bf16_t* __restrict__ A,
                                                 const bf16_t* __restrict__ Bt,
                                                 const float* __restrict__ bias,
                                                 void* __restrict__ Cout, int M, int N, int K,
                                                 int nx) {
  constexpr int WN = (TPB == 512) ? 4 : 2;   // waves along N
  constexpr int WM = (TPB / 64) / WN;        // waves along M (=2)
  constexpr int WTM = BM / WM;               // wave tile rows
  constexpr int WTN = BN / WN;               // wave tile cols
  constexpr int NI = WTM / 16;
  constexpr int NJ = WTN / 16;
  constexpr int PA = BM * 4 / TPB;           // A staging passes (16B/thread each)
  constexpr int PB = BN * 4 / TPB;
  __shared__ bf16_t Al[2][BM * 32];
  __shared__ bf16_t Bl[2][BN * 32];
  const int tid = threadIdx.x;
  const int lane = tid & 63;
  const int wid = tid >> 6;
  const int wm = wid / WN, wn = wid % WN;
  const int nwg = gridDim.x;
  const int cpx = nwg >> 3;
  const int swz = (blockIdx.x & 7) * cpx + (blockIdx.x >> 3);
  const int m0 = (swz / nx) * BM, n0 = (swz % nx) * BN;
  const int lr = lane & 15;
  const int lk = lane >> 4;

  f32x4 acc[NI][NJ] = {};

  auto STAGE = [&](int buf, int k0) {
#pragma unroll
    for (int p = 0; p < PA; ++p) {
      int o = p * TPB * 16 + tid * 16;
      int row = o >> 6, cb = o & 63;
      gld_lds16((const char*)A + ((size_t)(m0 + row) * K + k0) * 2 + cb,
                (char*)Al[buf] + o);
    }
#pragma unroll
    for (int p = 0; p < PB; ++p) {
      int o = p * TPB * 16 + tid * 16;
      int row = o >> 6, cb = o & 63;
      gld_lds16((const char*)Bt + ((size_t)(n0 + row) * K + k0) * 2 + cb,
                (char*)Bl[buf] + o);
    }
  };

  STAGE(0, 0);

  const int nk = K >> 5;
  for (int t = 0; t < nk; ++t) {
    const int cur = t & 1;
    asm volatile("s_waitcnt vmcnt(0)" ::: "memory");
    __builtin_amdgcn_s_barrier();
    if (t + 1 < nk) STAGE(cur ^ 1, (t + 1) << 5);
    bf16x8 af[NI], bfr[NJ];
#pragma unroll
    for (int i = 0; i < NI; ++i)
      af[i] = *(const bf16x8*)(Al[cur] + ((wm * WTM + i * 16 + lr) * 32 + lk * 8));
#pragma unroll
    for (int j = 0; j < NJ; ++j)
      bfr[j] = *(const bf16x8*)(Bl[cur] + ((wn * WTN + j * 16 + lr) * 32 + lk * 8));
#pragma unroll
    for (int i = 0; i < NI; ++i)
#pragma unroll
      for (int j = 0; j < NJ; ++j)
        acc[i][j] = MFMA16(af[i], bfr[j], acc[i][j]);
  }

#pragma unroll
  for (int i = 0; i < NI; ++i) {
    int grow = m0 + wm * WTM + i * 16 + lk * 4;
#pragma unroll
    for (int j = 0; j < NJ; ++j) {
      int gcol = n0 + wn * WTN + j * 16 + lr;
      float bv = bias[gcol];
      float scl = (SCALEQ && gcol < 1024) ? 0.18033688011112042f : 1.0f;
#pragma unroll
      for (int r = 0; r < 4; ++r) {
        float v = (acc[i][j][r] + bv) * scl;
        size_t off = (size_t)(grow + r) * N + gcol;
        if (BF16OUT)
          ((bf16_t*)Cout)[off] = f2bf(v);
        else
          ((float*)Cout)[off] = v;
      }
    }
  }
}

// ---------------- fused causal attention (swapped QK^T, K via LDS, static softmax) ----------------
// Parked (LDS-pipe/latency bound at ~50us, ~78% LDS utilization at 256B/clk).
// 1024 blocks, one q-tile each (balanced-quartet qt mapping); 4 waves x 16 q-rows;
// K staged once/block via global_load_lds (double-buffered, inverse-swizzled source
// + T2-swizzled b128 reads); Vt double-buffered via reg ping-pong (one raw
// barrier/step); counted vmcnt; swapped MFMAs; static softmax; packed epilogue.
__global__ __launch_bounds__(256) void k_attn(const bf16_t* __restrict__ qkv,
                                              bf16_t* __restrict__ score) {
  __shared__ bf16_t Kl[2][64 * 64];  // [buf][kv-row][chunk'] 16 KiB, swizzled chunks
  __shared__ bf16_t Vt[2][64 * 64];  // [buf][d][kv] swizzled, 16 KiB
  __shared__ bf16_t Pl[4][16 * 64];  // per-wave P [q][kv] swizzled, 8 KiB
  const int tid = threadIdx.x;
  const int lane = tid & 63;
  const int w = tid >> 6;
  const int lr = lane & 15, lk = lane >> 4;

  const int flat = blockIdx.x;
  const int g = flat >> 5;
  const int idx = g & 7;
  const int grp = g >> 3;
  const int qt = (grp == 0) ? (31 - idx)
               : (grp == 1) ? (15 - idx)
               : (grp == 2) ? (16 + idx)
                            : idx;  // balanced quartets
  const int bh = flat & 31;
  const int b = bh >> 4, h = bh & 15;

  const bf16_t* Qb = qkv + (size_t)b * 2048 * 3072 + h * 64;
  const bf16_t* Kb = Qb + 1024;
  const bf16_t* Vb = Qb + 2048;

  int d0c[2], kv2[2], krow[2], kchk[2];
#pragma unroll
  for (int p = 0; p < 2; ++p) {
    int e = p * 256 + tid;
    d0c[p] = (e & 15) * 4;
    kv2[p] = (e >> 4) * 2;
    krow[p] = e >> 3;
    kchk[p] = (e & 7) ^ (krow[p] & 7);
  }

  const int qr0 = qt * 64 + w * 16;
  const int q = qr0 + lr;  // this lane's q-row (swapped layout)
  const int jtEnd = qt + 1;

  bf16x8 qf[2];
#pragma unroll
  for (int ks = 0; ks < 2; ++ks)
    qf[ks] = *(const bf16x8*)(Qb + (size_t)(qr0 + lr) * 3072 + ks * 32 + lk * 8);

  f32x4 o[4] = {};
  float l = 0.f;

  // prologue: V(0)->Vt buf0 via regs (paired-kv b32 writes)
  {
    bf16x4 v0[2][2];
#pragma unroll
    for (int p = 0; p < 2; ++p) {
      v0[p][0] = *(const bf16x4*)(Vb + (size_t)kv2[p] * 3072 + d0c[p]);
      v0[p][1] = *(const bf16x4*)(Vb + (size_t)(kv2[p] + 1) * 3072 + d0c[p]);
    }
#pragma unroll
    for (int p = 0; p < 2; ++p)
#pragma unroll
      for (int j = 0; j < 4; ++j) {
        int d = d0c[p] + j;
        int addr = (d * 128 + kv2[p] * 2) ^ (((d & 7) ^ ((d >> 3) & 7)) << 4);
        *(unsigned*)((char*)Vt + addr) = pack2(v0[p][0][j], v0[p][1][j]);
      }
  }
  bf16x4 vrA[2][2], vrB[2][2];
#pragma unroll
  for (int p = 0; p < 2; ++p) {
    vrA[p][0] = *(const bf16x4*)(Vb + (size_t)(64 + kv2[p]) * 3072 + d0c[p]);
    vrA[p][1] = *(const bf16x4*)(Vb + (size_t)(64 + kv2[p] + 1) * 3072 + d0c[p]);
  }
#pragma unroll
  for (int p = 0; p < 2; ++p)
    gld_lds16((const char*)Kb + ((size_t)krow[p] * 3072 + kchk[p] * 8) * 2,
              (char*)Kl + (p * 256 + tid) * 16);

  auto STEP = [&](int jt, bf16x4 (&vrC)[2][2], bf16x4 (&vrN)[2][2], bool last) {
    const int kv0 = jt * 64;
    asm volatile("s_waitcnt lgkmcnt(0)" ::: "memory");
    __builtin_amdgcn_s_barrier();
    char* wbase = (char*)Vt + (((jt + 1) & 1) << 13);
#pragma unroll
    for (int p = 0; p < 2; ++p)
#pragma unroll
      for (int j = 0; j < 4; ++j) {
        int d = d0c[p] + j;
        int addr = (d * 128 + kv2[p] * 2) ^ (((d & 7) ^ ((d >> 3) & 7)) << 4);
        *(unsigned*)(wbase + addr) = pack2(vrC[p][0][j], vrC[p][1][j]);
      }
    if (!last) {
      const int kvV = (kv0 + 128 < 2048) ? kv0 + 128 : 1920;
#pragma unroll
      for (int p = 0; p < 2; ++p) {
        vrN[p][0] = *(const bf16x4*)(Vb + (size_t)(kvV + kv2[p]) * 3072 + d0c[p]);
        vrN[p][1] = *(const bf16x4*)(Vb + (size_t)(kvV + kv2[p] + 1) * 3072 + d0c[p]);
      }
      char* kbase = (char*)Kl + (((jt + 1) & 1) << 13);
#pragma unroll
      for (int p = 0; p < 2; ++p)
        gld_lds16((const char*)Kb + ((size_t)(kv0 + 64 + krow[p]) * 3072 + kchk[p] * 8) * 2,
                  kbase + (p * 256 + tid) * 16);
      asm volatile("s_waitcnt vmcnt(6)" ::: "memory");
    } else {
      asm volatile("s_waitcnt vmcnt(0)" ::: "memory");
    }
    const char* kread = (const char*)Kl + ((jt & 1) << 13);
    bf16x8 kf[4][2];
#pragma unroll
    for (int nc = 0; nc < 4; ++nc) {
      const char* rowp = kread + (nc * 16 + lr) * 128;
      kf[nc][0] = *(const bf16x8*)(rowp + ((lk ^ (lr & 7)) << 4));
      kf[nc][1] = *(const bf16x8*)(rowp + (((4 | lk) ^ (lr & 7)) << 4));
    }
    f32x4 s[4];
    __builtin_amdgcn_s_setprio(1);
#pragma unroll
    for (int nc = 0; nc < 4; ++nc) {
      f32x4 z = {};
      z = MFMA16(kf[nc][0], qf[0], z);
      z = MFMA16(kf[nc][1], qf[1], z);
      s[nc] = z;
    }
    __builtin_amdgcn_s_setprio(0);
    if (kv0 + 63 > qr0) {
#pragma unroll
      for (int nc = 0; nc < 4; ++nc)
#pragma unroll
        for (int r = 0; r < 4; ++r) {
          int kvi = kv0 + nc * 16 + lk * 4 + r;
          if (kvi > q) s[nc][r] = -INFINITY;
        }
    }
#pragma unroll
    for (int nc = 0; nc < 4; ++nc)
#pragma unroll
      for (int r = 0; r < 4; ++r) {
        float p = exp2f(s[nc][r]);
        s[nc][r] = p;
        l += p;
      }
    bf16_t* Pw = Pl[w];
#pragma unroll
    for (int nc = 0; nc < 4; ++nc) {
      uint2 u;
      u.x = cvt_pk_bf16(s[nc][0], s[nc][1]);
      u.y = cvt_pk_bf16(s[nc][2], s[nc][3]);
      int addr = (lr * 128 + (nc * 16 + lk * 4) * 2) ^ ((lr & 7) << 4);
      *(uint2*)((char*)Pw + addr) = u;
    }
    const char* rbase = (const char*)Vt + ((jt & 1) << 13);
    bf16x8 pa[2];
#pragma unroll
    for (int ks = 0; ks < 2; ++ks) {
      int addr = (lr * 128 + ks * 64 + lk * 16) ^ ((lr & 7) << 4);
      pa[ks] = *(const bf16x8*)((const char*)Pl[w] + addr);
    }
    __builtin_amdgcn_s_setprio(1);
#pragma unroll
    for (int db = 0; db < 4; ++db)
#pragma unroll
      for (int ks = 0; ks < 2; ++ks) {
        int d = db * 16 + lr;
        int addr = (d * 128 + ks * 64 + lk * 16) ^ (((d & 7) ^ ((d >> 3) & 7)) << 4);
        bf16x8 vb = *(const bf16x8*)(rbase + addr);
        o[db] = MFMA16(vb, pa[ks], o[db]);
      }
    __builtin_amdgcn_s_setprio(0);
  };

  int jt = 0;
  for (;;) {
    STEP(jt, vrA, vrB, jt + 1 == jtEnd);
    if (++jt == jtEnd) break;
    STEP(jt, vrB, vrA, jt + 1 == jtEnd);
    if (++jt == jtEnd) break;
  }

  l += __shfl_xor(l, 16);
  l += __shfl_xor(l, 32);
  const float rl = 1.0f / l;
  bf16_t* orow = score + (size_t)(b * 2048 + q) * 1024 + h * 64 + lk * 4;
#pragma unroll
  for (int db = 0; db < 4; ++db) {
    unsigned w0 = cvt_pk_bf16(o[db][0] * rl, o[db][1] * rl);
    unsigned w1 = cvt_pk_bf16(o[db][2] * rl, o[db][3] * rl);
    uint2 pkt; pkt.x = w0; pkt.y = w1;
    *(uint2*)(orow + db * 16) = pkt;
  }
}

extern "C" void kernel_launch(void* const* d_in, const int* in_sizes, int n_in,
                              void* d_out, int out_size, void* d_ws, size_t ws_size,
                              hipStream_t stream) {
  const float* X  = (const float*)d_in[0];  // [2,2048,1024]
  const float* Wa = (const float*)d_in[1];  // [1024,3072]
  const float* ba = (const float*)d_in[2];  // [3072]
  const float* Wp = (const float*)d_in[3];  // [1024,1024]
  const float* bp = (const float*)d_in[4];  // [1024]
  float* out = (float*)d_out;               // [2,2048,1024] fp32

  char* ws = (char*)d_ws;
  bf16_t* Xb  = (bf16_t*)ws;                          // 8 MiB (reused as score)
  bf16_t* WaT = (bf16_t*)(ws + (size_t)(8u << 20));   // 6 MiB: W_attn^T [3072][1024]
  bf16_t* WpT = (bf16_t*)(ws + (size_t)(14u << 20));  // 2 MiB: W_proj^T [1024][1024]
  bf16_t* QKV = (bf16_t*)(ws + (size_t)(16u << 20));  // 24 MiB: [4096][3072]
  bf16_t* S_  = Xb;

  // fused prep: X convert (2048 blocks) + Wa transpose (768) + Wp transpose (256)
  k_prep<<<3072, 256, 0, stream>>>(X, Xb, Wa, WaT, Wp, WpT);
  // QKV: 128x128 tile, 512 threads, depth-1 pipeline -> 768 blocks (L2-optimal)
  k_gemm_bt<true, true, 128, 128, 512><<<768, 512, 0, stream>>>(Xb, WaT, ba, QKV, 4096, 3072, 1024, 24);
  k_attn<<<1024, 256, 0, stream>>>(QKV, S_);
  // proj: 64x64 tile, 256 threads -> 1024 blocks = 4/CU (B L2-resident)
  k_gemm_bt<false, false, 64, 64, 256><<<1024, 256, 0, stream>>>(S_, WpT, bp, out, 4096, 1024, 1024, 16);
}

// Round 23
// 103.710 us; speedup vs baseline: 1.2375x; 1.0450x over previous
//
#include <hip/hip_runtime.h>
#include <hip/hip_bf16.h>

typedef unsigned short bf16_t;
typedef __attribute__((ext_vector_type(8))) short bf16x8;
typedef __attribute__((ext_vector_type(4))) short bf16x4;
typedef __attribute__((ext_vector_type(4))) float f32x4;

#define MFMA16(a, b, c) __builtin_amdgcn_mfma_f32_16x16x32_bf16((a), (b), (c), 0, 0, 0)

__device__ __forceinline__ bf16_t f2bf(float f) {
  union { float f; unsigned u; } v; v.f = f;
  unsigned u = v.u;
  u += 0x7FFFu + ((u >> 16) & 1u);
  return (bf16_t)(u >> 16);
}

// packed fp32x2 -> bf16x2 (RNE), one VALU op
__device__ __forceinline__ unsigned cvt_pk_bf16(float lo, float hi) {
  unsigned r;
  asm volatile("v_cvt_pk_bf16_f32 %0, %1, %2" : "=v"(r) : "v"(lo), "v"(hi));
  return r;
}

__device__ __forceinline__ unsigned pack2(short lo, short hi) {
  return ((unsigned)(unsigned short)lo) | ((unsigned)(unsigned short)hi << 16);
}

__device__ __forceinline__ void gld_lds16(const void* g, void* l) {
  __builtin_amdgcn_global_load_lds(
      (const __attribute__((address_space(1))) unsigned int*)g,
      (__attribute__((address_space(3))) unsigned int*)l, 16, 0, 0);
}

// ---------------- fused prep: X f32->bf16 + transpose both weights (R22-verified) ----------------
__global__ __launch_bounds__(256) void k_prep(const float* __restrict__ X,
                                              bf16_t* __restrict__ Xb,
                                              const float* __restrict__ Wa,
                                              bf16_t* __restrict__ WaT,
                                              const float* __restrict__ Wp,
                                              bf16_t* __restrict__ WpT) {
  __shared__ bf16_t t[64][65];
  const int blk = blockIdx.x;
  const int tid = threadIdx.x;
  if (blk < 2048) {
    int i = blk * 256 + tid;
    const float4* p = (const float4*)X + (size_t)i * 2;
    float4 a = p[0], b = p[1];
    bf16x8 o;
    o[0] = (short)f2bf(a.x); o[1] = (short)f2bf(a.y); o[2] = (short)f2bf(a.z); o[3] = (short)f2bf(a.w);
    o[4] = (short)f2bf(b.x); o[5] = (short)f2bf(b.y); o[6] = (short)f2bf(b.z); o[7] = (short)f2bf(b.w);
    *((bf16x8*)Xb + i) = o;
    return;
  }
  const bool wa = (blk < 2816);
  const int bx = wa ? (blk - 2048) : (blk - 2816);
  const int NX = wa ? 48 : 16;
  const int N = wa ? 3072 : 1024;
  const int K = 1024;
  const float* W = wa ? Wa : Wp;
  bf16_t* Wt = wa ? WaT : WpT;
  const int n0 = (bx % NX) * 64, k0 = (bx / NX) * 64;
#pragma unroll
  for (int p = 0; p < 16; ++p) {
    int lin = p * 256 + tid;
    int r = lin >> 6, c = lin & 63;
    t[r][c] = f2bf(W[(size_t)(k0 + r) * N + n0 + c]);
  }
  __syncthreads();
#pragma unroll
  for (int p = 0; p < 16; ++p) {
    int lin = p * 256 + tid;
    int nr = lin >> 6, kc = lin & 63;
    Wt[(size_t)(n0 + nr) * K + k0 + kc] = t[kc][nr];
  }
}

// ---------------- QKV GEMM: BK=64, half the barrier events (R23) ----------------
// 41us/32 iters = 3070cy/iter vs ~1900cy of pipe work -> barrier-rendezvous bound.
// BK=64 runs 16 MFMA-rich iters instead of 32 (2 barriers each) at the same total
// staging traffic. LDS rows are 128B -> b128 frag reads would be 16-way conflicted
// (G4); fixed with the attn-verified chunk-XOR: stage global chunk c^(row&7) into
// linear slot c, read at offset (c^(row&7))<<4 (16 lr-lanes span 8 chunk groups,
// 2 lanes/group = free). Fragments loaded per-kk to keep VGPR under the 85-reg
// 6-waves/SIMD limit. 128x128 tile, 8 waves 2x4, 768 blocks (L2-optimal per R15/R21).
template <bool SCALEQ>
__global__ __launch_bounds__(512) void k_gemm_qkv(const bf16_t* __restrict__ A,
                                                  const bf16_t* __restrict__ Bt,
                                                  const float* __restrict__ bias,
                                                  bf16_t* __restrict__ Cout,
                                                  int M, int N, int K, int nx) {
  __shared__ bf16_t Al[128 * 64];  // 16 KiB, chunk-swizzled
  __shared__ bf16_t Bl[128 * 64];  // 16 KiB, chunk-swizzled
  const int tid = threadIdx.x;
  const int lane = tid & 63;
  const int wid = tid >> 6;
  const int wm = wid >> 2, wn = wid & 3;  // 2x4 wave grid, wave tile 64x32
  const int nwg = gridDim.x;
  const int cpx = nwg >> 3;
  const int swz = (blockIdx.x & 7) * cpx + (blockIdx.x >> 3);
  const int m0 = (swz / nx) * 128, n0 = (swz % nx) * 128;
  const int lr = lane & 15;
  const int lk = lane >> 4;

  // staging coords: tile = 128 rows x 128B = 1024 chunks; 512 threads x 2 passes
  int srow[2], schk[2];
#pragma unroll
  for (int p = 0; p < 2; ++p) {
    int t2 = p * 512 + tid;
    srow[p] = t2 >> 3;
    schk[p] = (t2 & 7) ^ (srow[p] & 7);
  }

  f32x4 acc[4][2] = {};

  for (int k0 = 0; k0 < K; k0 += 64) {
    __syncthreads();
#pragma unroll
    for (int p = 0; p < 2; ++p) {
      gld_lds16((const char*)A + ((size_t)(m0 + srow[p]) * K + k0 + schk[p] * 8) * 2,
                (char*)Al + (p * 512 + tid) * 16);
      gld_lds16((const char*)Bt + ((size_t)(n0 + srow[p]) * K + k0 + schk[p] * 8) * 2,
                (char*)Bl + (p * 512 + tid) * 16);
    }
    __syncthreads();
#pragma unroll
    for (int kk = 0; kk < 2; ++kk) {
      bf16x8 af[4], bfr[2];
#pragma unroll
      for (int i = 0; i < 4; ++i) {
        int row = wm * 64 + i * 16 + lr;
        af[i] = *(const bf16x8*)((const char*)Al + row * 128 + (((kk * 4 + lk) ^ (row & 7)) << 4));
      }
#pragma unroll
      for (int j = 0; j < 2; ++j) {
        int row = wn * 32 + j * 16 + lr;
        bfr[j] = *(const bf16x8*)((const char*)Bl + row * 128 + (((kk * 4 + lk) ^ (row & 7)) << 4));
      }
#pragma unroll
      for (int i = 0; i < 4; ++i)
#pragma unroll
        for (int j = 0; j < 2; ++j)
          acc[i][j] = MFMA16(af[i], bfr[j], acc[i][j]);
    }
  }

#pragma unroll
  for (int i = 0; i < 4; ++i) {
    int grow = m0 + wm * 64 + i * 16 + lk * 4;
#pragma unroll
    for (int j = 0; j < 2; ++j) {
      int gcol = n0 + wn * 32 + j * 16 + lr;
      float bv = bias[gcol];
      float scl = (SCALEQ && gcol < 1024) ? 0.18033688011112042f : 1.0f;
#pragma unroll
      for (int r = 0; r < 4; ++r) {
        float v = (acc[i][j][r] + bv) * scl;
        Cout[(size_t)(grow + r) * N + gcol] = f2bf(v);
      }
    }
  }
}

// ---------------- proj GEMM (R22-verified depth-1 pipeline, 64x64, 256T) ----------------
template <bool BF16OUT, int BM, int BN, int TPB>
__global__ __launch_bounds__(TPB) void k_gemm_bt(const bf16_t* __restrict__ A,
                                                 const bf16_t* __restrict__ Bt,
                                                 const float* __restrict__ bias,
                                                 void* __restrict__ Cout, int M, int N, int K,
                                                 int nx) {
  constexpr int WN = (TPB == 512) ? 4 : 2;
  constexpr int WM = (TPB / 64) / WN;
  constexpr int WTM = BM / WM;
  constexpr int WTN = BN / WN;
  constexpr int NI = WTM / 16;
  constexpr int NJ = WTN / 16;
  constexpr int PA = BM * 4 / TPB;
  constexpr int PB = BN * 4 / TPB;
  __shared__ bf16_t Al[2][BM * 32];
  __shared__ bf16_t Bl[2][BN * 32];
  const int tid = threadIdx.x;
  const int lane = tid & 63;
  const int wid = tid >> 6;
  const int wm = wid / WN, wn = wid % WN;
  const int nwg = gridDim.x;
  const int cpx = nwg >> 3;
  const int swz = (blockIdx.x & 7) * cpx + (blockIdx.x >> 3);
  const int m0 = (swz / nx) * BM, n0 = (swz % nx) * BN;
  const int lr = lane & 15;
  const int lk = lane >> 4;

  f32x4 acc[NI][NJ] = {};

  auto STAGE = [&](int buf, int k0) {
#pragma unroll
    for (int p = 0; p < PA; ++p) {
      int o = p * TPB * 16 + tid * 16;
      int row = o >> 6, cb = o & 63;
      gld_lds16((const char*)A + ((size_t)(m0 + row) * K + k0) * 2 + cb,
                (char*)Al[buf] + o);
    }
#pragma unroll
    for (int p = 0; p < PB; ++p) {
      int o = p * TPB * 16 + tid * 16;
      int row = o >> 6, cb = o & 63;
      gld_lds16((const char*)Bt + ((size_t)(n0 + row) * K + k0) * 2 + cb,
                (char*)Bl[buf] + o);
    }
  };

  STAGE(0, 0);

  const int nk = K >> 5;
  for (int t = 0; t < nk; ++t) {
    const int cur = t & 1;
    asm volatile("s_waitcnt vmcnt(0)" ::: "memory");
    __builtin_amdgcn_s_barrier();
    if (t + 1 < nk) STAGE(cur ^ 1, (t + 1) << 5);
    bf16x8 af[NI], bfr[NJ];
#pragma unroll
    for (int i = 0; i < NI; ++i)
      af[i] = *(const bf16x8*)(Al[cur] + ((wm * WTM + i * 16 + lr) * 32 + lk * 8));
#pragma unroll
    for (int j = 0; j < NJ; ++j)
      bfr[j] = *(const bf16x8*)(Bl[cur] + ((wn * WTN + j * 16 + lr) * 32 + lk * 8));
#pragma unroll
    for (int i = 0; i < NI; ++i)
#pragma unroll
      for (int j = 0; j < NJ; ++j)
        acc[i][j] = MFMA16(af[i], bfr[j], acc[i][j]);
  }

#pragma unroll
  for (int i = 0; i < NI; ++i) {
    int grow = m0 + wm * WTM + i * 16 + lk * 4;
#pragma unroll
    for (int j = 0; j < NJ; ++j) {
      int gcol = n0 + wn * WTN + j * 16 + lr;
      float bv = bias[gcol];
#pragma unroll
      for (int r = 0; r < 4; ++r) {
        float v = acc[i][j][r] + bv;
        size_t off = (size_t)(grow + r) * N + gcol;
        if (BF16OUT)
          ((bf16_t*)Cout)[off] = f2bf(v);
        else
          ((float*)Cout)[off] = v;
      }
    }
  }
}

// ---------------- fused causal attention (R22-verified; parked) ----------------
__global__ __launch_bounds__(256) void k_attn(const bf16_t* __restrict__ qkv,
                                              bf16_t* __restrict__ score) {
  __shared__ bf16_t Kl[2][64 * 64];
  __shared__ bf16_t Vt[2][64 * 64];
  __shared__ bf16_t Pl[4][16 * 64];
  const int tid = threadIdx.x;
  const int lane = tid & 63;
  const int w = tid >> 6;
  const int lr = lane & 15, lk = lane >> 4;

  const int flat = blockIdx.x;
  const int g = flat >> 5;
  const int idx = g & 7;
  const int grp = g >> 3;
  const int qt = (grp == 0) ? (31 - idx)
               : (grp == 1) ? (15 - idx)
               : (grp == 2) ? (16 + idx)
                            : idx;
  const int bh = flat & 31;
  const int b = bh >> 4, h = bh & 15;

  const bf16_t* Qb = qkv + (size_t)b * 2048 * 3072 + h * 64;
  const bf16_t* Kb = Qb + 1024;
  const bf16_t* Vb = Qb + 2048;

  int d0c[2], kv2[2], krow[2], kchk[2];
#pragma unroll
  for (int p = 0; p < 2; ++p) {
    int e = p * 256 + tid;
    d0c[p] = (e & 15) * 4;
    kv2[p] = (e >> 4) * 2;
    krow[p] = e >> 3;
    kchk[p] = (e & 7) ^ (krow[p] & 7);
  }

  const int qr0 = qt * 64 + w * 16;
  const int q = qr0 + lr;
  const int jtEnd = qt + 1;

  bf16x8 qf[2];
#pragma unroll
  for (int ks = 0; ks < 2; ++ks)
    qf[ks] = *(const bf16x8*)(Qb + (size_t)(qr0 + lr) * 3072 + ks * 32 + lk * 8);

  f32x4 o[4] = {};
  float l = 0.f;

  {
    bf16x4 v0[2][2];
#pragma unroll
    for (int p = 0; p < 2; ++p) {
      v0[p][0] = *(const bf16x4*)(Vb + (size_t)kv2[p] * 3072 + d0c[p]);
      v0[p][1] = *(const bf16x4*)(Vb + (size_t)(kv2[p] + 1) * 3072 + d0c[p]);
    }
#pragma unroll
    for (int p = 0; p < 2; ++p)
#pragma unroll
      for (int j = 0; j < 4; ++j) {
        int d = d0c[p] + j;
        int addr = (d * 128 + kv2[p] * 2) ^ (((d & 7) ^ ((d >> 3) & 7)) << 4);
        *(unsigned*)((char*)Vt + addr) = pack2(v0[p][0][j], v0[p][1][j]);
      }
  }
  bf16x4 vrA[2][2], vrB[2][2];
#pragma unroll
  for (int p = 0; p < 2; ++p) {
    vrA[p][0] = *(const bf16x4*)(Vb + (size_t)(64 + kv2[p]) * 3072 + d0c[p]);
    vrA[p][1] = *(const bf16x4*)(Vb + (size_t)(64 + kv2[p] + 1) * 3072 + d0c[p]);
  }
#pragma unroll
  for (int p = 0; p < 2; ++p)
    gld_lds16((const char*)Kb + ((size_t)krow[p] * 3072 + kchk[p] * 8) * 2,
              (char*)Kl + (p * 256 + tid) * 16);

  auto STEP = [&](int jt, bf16x4 (&vrC)[2][2], bf16x4 (&vrN)[2][2], bool last) {
    const int kv0 = jt * 64;
    asm volatile("s_waitcnt lgkmcnt(0)" ::: "memory");
    __builtin_amdgcn_s_barrier();
    char* wbase = (char*)Vt + (((jt + 1) & 1) << 13);
#pragma unroll
    for (int p = 0; p < 2; ++p)
#pragma unroll
      for (int j = 0; j < 4; ++j) {
        int d = d0c[p] + j;
        int addr = (d * 128 + kv2[p] * 2) ^ (((d & 7) ^ ((d >> 3) & 7)) << 4);
        *(unsigned*)(wbase + addr) = pack2(vrC[p][0][j], vrC[p][1][j]);
      }
    if (!last) {
      const int kvV = (kv0 + 128 < 2048) ? kv0 + 128 : 1920;
#pragma unroll
      for (int p = 0; p < 2; ++p) {
        vrN[p][0] = *(const bf16x4*)(Vb + (size_t)(kvV + kv2[p]) * 3072 + d0c[p]);
        vrN[p][1] = *(const bf16x4*)(Vb + (size_t)(kvV + kv2[p] + 1) * 3072 + d0c[p]);
      }
      char* kbase = (char*)Kl + (((jt + 1) & 1) << 13);
#pragma unroll
      for (int p = 0; p < 2; ++p)
        gld_lds16((const char*)Kb + ((size_t)(kv0 + 64 + krow[p]) * 3072 + kchk[p] * 8) * 2,
                  kbase + (p * 256 + tid) * 16);
      asm volatile("s_waitcnt vmcnt(6)" ::: "memory");
    } else {
      asm volatile("s_waitcnt vmcnt(0)" ::: "memory");
    }
    const char* kread = (const char*)Kl + ((jt & 1) << 13);
    bf16x8 kf[4][2];
#pragma unroll
    for (int nc = 0; nc < 4; ++nc) {
      const char* rowp = kread + (nc * 16 + lr) * 128;
      kf[nc][0] = *(const bf16x8*)(rowp + ((lk ^ (lr & 7)) << 4));
      kf[nc][1] = *(const bf16x8*)(rowp + (((4 | lk) ^ (lr & 7)) << 4));
    }
    f32x4 s[4];
    __builtin_amdgcn_s_setprio(1);
#pragma unroll
    for (int nc = 0; nc < 4; ++nc) {
      f32x4 z = {};
      z = MFMA16(kf[nc][0], qf[0], z);
      z = MFMA16(kf[nc][1], qf[1], z);
      s[nc] = z;
    }
    __builtin_amdgcn_s_setprio(0);
    if (kv0 + 63 > qr0) {
#pragma unroll
      for (int nc = 0; nc < 4; ++nc)
#pragma unroll
        for (int r = 0; r < 4; ++r) {
          int kvi = kv0 + nc * 16 + lk * 4 + r;
          if (kvi > q) s[nc][r] = -INFINITY;
        }
    }
#pragma unroll
    for (int nc = 0; nc < 4; ++nc)
#pragma unroll
      for (int r = 0; r < 4; ++r) {
        float p = exp2f(s[nc][r]);
        s[nc][r] = p;
        l += p;
      }
    bf16_t* Pw = Pl[w];
#pragma unroll
    for (int nc = 0; nc < 4; ++nc) {
      uint2 u;
      u.x = cvt_pk_bf16(s[nc][0], s[nc][1]);
      u.y = cvt_pk_bf16(s[nc][2], s[nc][3]);
      int addr = (lr * 128 + (nc * 16 + lk * 4) * 2) ^ ((lr & 7) << 4);
      *(uint2*)((char*)Pw + addr) = u;
    }
    const char* rbase = (const char*)Vt + ((jt & 1) << 13);
    bf16x8 pa[2];
#pragma unroll
    for (int ks = 0; ks < 2; ++ks) {
      int addr = (lr * 128 + ks * 64 + lk * 16) ^ ((lr & 7) << 4);
      pa[ks] = *(const bf16x8*)((const char*)Pl[w] + addr);
    }
    __builtin_amdgcn_s_setprio(1);
#pragma unroll
    for (int db = 0; db < 4; ++db)
#pragma unroll
      for (int ks = 0; ks < 2; ++ks) {
        int d = db * 16 + lr;
        int addr = (d * 128 + ks * 64 + lk * 16) ^ (((d & 7) ^ ((d >> 3) & 7)) << 4);
        bf16x8 vb = *(const bf16x8*)(rbase + addr);
        o[db] = MFMA16(vb, pa[ks], o[db]);
      }
    __builtin_amdgcn_s_setprio(0);
  };

  int jt = 0;
  for (;;) {
    STEP(jt, vrA, vrB, jt + 1 == jtEnd);
    if (++jt == jtEnd) break;
    STEP(jt, vrB, vrA, jt + 1 == jtEnd);
    if (++jt == jtEnd) break;
  }

  l += __shfl_xor(l, 16);
  l += __shfl_xor(l, 32);
  const float rl = 1.0f / l;
  bf16_t* orow = score + (size_t)(b * 2048 + q) * 1024 + h * 64 + lk * 4;
#pragma unroll
  for (int db = 0; db < 4; ++db) {
    unsigned w0 = cvt_pk_bf16(o[db][0] * rl, o[db][1] * rl);
    unsigned w1 = cvt_pk_bf16(o[db][2] * rl, o[db][3] * rl);
    uint2 pkt; pkt.x = w0; pkt.y = w1;
    *(uint2*)(orow + db * 16) = pkt;
  }
}

extern "C" void kernel_launch(void* const* d_in, const int* in_sizes, int n_in,
                              void* d_out, int out_size, void* d_ws, size_t ws_size,
                              hipStream_t stream) {
  const float* X  = (const float*)d_in[0];  // [2,2048,1024]
  const float* Wa = (const float*)d_in[1];  // [1024,3072]
  const float* ba = (const float*)d_in[2];  // [3072]
  const float* Wp = (const float*)d_in[3];  // [1024,1024]
  const float* bp = (const float*)d_in[4];  // [1024]
  float* out = (float*)d_out;               // [2,2048,1024] fp32

  char* ws = (char*)d_ws;
  bf16_t* Xb  = (bf16_t*)ws;                          // 8 MiB (reused as score)
  bf16_t* WaT = (bf16_t*)(ws + (size_t)(8u << 20));   // 6 MiB: W_attn^T [3072][1024]
  bf16_t* WpT = (bf16_t*)(ws + (size_t)(14u << 20));  // 2 MiB: W_proj^T [1024][1024]
  bf16_t* QKV = (bf16_t*)(ws + (size_t)(16u << 20));  // 24 MiB: [4096][3072]
  bf16_t* S_  = Xb;

  k_prep<<<3072, 256, 0, stream>>>(X, Xb, Wa, WaT, Wp, WpT);
  // QKV: BK=64 (16 iters, half the barrier events), 128x128, 512T, 768 blocks
  k_gemm_qkv<true><<<768, 512, 0, stream>>>(Xb, WaT, ba, QKV, 4096, 3072, 1024, 24);
  k_attn<<<1024, 256, 0, stream>>>(QKV, S_);
  // proj: 64x64 tile, 256 threads, depth-1 pipeline -> 1024 blocks = 4/CU
  k_gemm_bt<false, 64, 64, 256><<<1024, 256, 0, stream>>>(S_, WpT, bp, out, 4096, 1024, 1024, 16);
}

// Round 24
// 102.804 us; speedup vs baseline: 1.2484x; 1.0088x over previous
//
#include <hip/hip_runtime.h>
#include <hip/hip_bf16.h>

typedef unsigned short bf16_t;
typedef __attribute__((ext_vector_type(8))) short bf16x8;
typedef __attribute__((ext_vector_type(4))) short bf16x4;
typedef __attribute__((ext_vector_type(4))) float f32x4;

#define MFMA16(a, b, c) __builtin_amdgcn_mfma_f32_16x16x32_bf16((a), (b), (c), 0, 0, 0)

__device__ __forceinline__ bf16_t f2bf(float f) {
  union { float f; unsigned u; } v; v.f = f;
  unsigned u = v.u;
  u += 0x7FFFu + ((u >> 16) & 1u);
  return (bf16_t)(u >> 16);
}

// packed fp32x2 -> bf16x2 (RNE), one VALU op
__device__ __forceinline__ unsigned cvt_pk_bf16(float lo, float hi) {
  unsigned r;
  asm volatile("v_cvt_pk_bf16_f32 %0, %1, %2" : "=v"(r) : "v"(lo), "v"(hi));
  return r;
}

__device__ __forceinline__ unsigned pack2(short lo, short hi) {
  return ((unsigned)(unsigned short)lo) | ((unsigned)(unsigned short)hi << 16);
}

__device__ __forceinline__ void gld_lds16(const void* g, void* l) {
  __builtin_amdgcn_global_load_lds(
      (const __attribute__((address_space(1))) unsigned int*)g,
      (__attribute__((address_space(3))) unsigned int*)l, 16, 0, 0);
}

// ---------------- fused prep: X f32->bf16 + transpose both weights (R22-verified) ----------------
__global__ __launch_bounds__(256) void k_prep(const float* __restrict__ X,
                                              bf16_t* __restrict__ Xb,
                                              const float* __restrict__ Wa,
                                              bf16_t* __restrict__ WaT,
                                              const float* __restrict__ Wp,
                                              bf16_t* __restrict__ WpT) {
  __shared__ bf16_t t[64][65];
  const int blk = blockIdx.x;
  const int tid = threadIdx.x;
  if (blk < 2048) {
    int i = blk * 256 + tid;
    const float4* p = (const float4*)X + (size_t)i * 2;
    float4 a = p[0], b = p[1];
    bf16x8 o;
    o[0] = (short)f2bf(a.x); o[1] = (short)f2bf(a.y); o[2] = (short)f2bf(a.z); o[3] = (short)f2bf(a.w);
    o[4] = (short)f2bf(b.x); o[5] = (short)f2bf(b.y); o[6] = (short)f2bf(b.z); o[7] = (short)f2bf(b.w);
    *((bf16x8*)Xb + i) = o;
    return;
  }
  const bool wa = (blk < 2816);
  const int bx = wa ? (blk - 2048) : (blk - 2816);
  const int NX = wa ? 48 : 16;
  const int N = wa ? 3072 : 1024;
  const int K = 1024;
  const float* W = wa ? Wa : Wp;
  bf16_t* Wt = wa ? WaT : WpT;
  const int n0 = (bx % NX) * 64, k0 = (bx / NX) * 64;
#pragma unroll
  for (int p = 0; p < 16; ++p) {
    int lin = p * 256 + tid;
    int r = lin >> 6, c = lin & 63;
    t[r][c] = f2bf(W[(size_t)(k0 + r) * N + n0 + c]);
  }
  __syncthreads();
#pragma unroll
  for (int p = 0; p < 16; ++p) {
    int lin = p * 256 + tid;
    int nr = lin >> 6, kc = lin & 63;
    Wt[(size_t)(n0 + nr) * K + k0 + kc] = t[kc][nr];
  }
}

// ---------------- GEMM-BT, BK=64 (R23-verified, generalized R24) ----------------
// Half the barrier events of BK=32 (16 iters for K=1024) — R23 measured QKV 41->36us.
// LDS rows are 128B; chunk-XOR staging (inverse-swizzled gld_lds SOURCE, linear
// dest) + read offset ((kk*4+lk)^(row&7))<<4 keeps b128 frag reads conflict-free
// (16 lr-lanes span 8 chunk groups, 2 lanes/group = free). Fragments loaded per-kk
// to bound VGPR. QKV: 128x128/512T/768 blocks (L2-optimal per R15/R21).
// proj: 64x64/256T/1024 blocks (B L2-resident, 4 blocks/CU).
template <bool BF16OUT, bool SCALEQ, int BM, int BN, int TPB>
__global__ __launch_bounds__(TPB) void k_gemm64(const bf16_t* __restrict__ A,
                                                const bf16_t* __restrict__ Bt,
                                                const float* __restrict__ bias,
                                                void* __restrict__ Cout,
                                                int M, int N, int K, int nx) {
  constexpr int WN = (TPB == 512) ? 4 : 2;   // waves along N
  constexpr int WM = (TPB / 64) / WN;        // waves along M
  constexpr int WTM = BM / WM;               // wave tile rows
  constexpr int WTN = BN / WN;               // wave tile cols
  constexpr int NI = WTM / 16;
  constexpr int NJ = WTN / 16;
  constexpr int PA = BM * 8 / TPB;           // A staging passes (16B chunks)
  constexpr int PB = BN * 8 / TPB;
  __shared__ bf16_t Al[BM * 64];  // [row][128B], chunk-swizzled
  __shared__ bf16_t Bl[BN * 64];
  const int tid = threadIdx.x;
  const int lane = tid & 63;
  const int wid = tid >> 6;
  const int wm = wid / WN, wn = wid % WN;
  const int nwg = gridDim.x;
  const int cpx = nwg >> 3;
  const int swz = (blockIdx.x & 7) * cpx + (blockIdx.x >> 3);
  const int m0 = (swz / nx) * BM, n0 = (swz % nx) * BN;
  const int lr = lane & 15;
  const int lk = lane >> 4;

  // staging coords: thread t2 stages global chunk (t2&7)^(row&7) of row t2>>3
  int srowA[PA], schkA[PA], srowB[PB], schkB[PB];
#pragma unroll
  for (int p = 0; p < PA; ++p) {
    int t2 = p * TPB + tid;
    srowA[p] = t2 >> 3;
    schkA[p] = (t2 & 7) ^ (srowA[p] & 7);
  }
#pragma unroll
  for (int p = 0; p < PB; ++p) {
    int t2 = p * TPB + tid;
    srowB[p] = t2 >> 3;
    schkB[p] = (t2 & 7) ^ (srowB[p] & 7);
  }

  f32x4 acc[NI][NJ] = {};

  for (int k0 = 0; k0 < K; k0 += 64) {
    __syncthreads();
#pragma unroll
    for (int p = 0; p < PA; ++p)
      gld_lds16((const char*)A + ((size_t)(m0 + srowA[p]) * K + k0 + schkA[p] * 8) * 2,
                (char*)Al + (p * TPB + tid) * 16);
#pragma unroll
    for (int p = 0; p < PB; ++p)
      gld_lds16((const char*)Bt + ((size_t)(n0 + srowB[p]) * K + k0 + schkB[p] * 8) * 2,
                (char*)Bl + (p * TPB + tid) * 16);
    __syncthreads();
#pragma unroll
    for (int kk = 0; kk < 2; ++kk) {
      bf16x8 af[NI], bfr[NJ];
#pragma unroll
      for (int i = 0; i < NI; ++i) {
        int row = wm * WTM + i * 16 + lr;
        af[i] = *(const bf16x8*)((const char*)Al + row * 128 + (((kk * 4 + lk) ^ (row & 7)) << 4));
      }
#pragma unroll
      for (int j = 0; j < NJ; ++j) {
        int row = wn * WTN + j * 16 + lr;
        bfr[j] = *(const bf16x8*)((const char*)Bl + row * 128 + (((kk * 4 + lk) ^ (row & 7)) << 4));
      }
#pragma unroll
      for (int i = 0; i < NI; ++i)
#pragma unroll
        for (int j = 0; j < NJ; ++j)
          acc[i][j] = MFMA16(af[i], bfr[j], acc[i][j]);
    }
  }

#pragma unroll
  for (int i = 0; i < NI; ++i) {
    int grow = m0 + wm * WTM + i * 16 + lk * 4;
#pragma unroll
    for (int j = 0; j < NJ; ++j) {
      int gcol = n0 + wn * WTN + j * 16 + lr;
      float bv = bias[gcol];
      float scl = (SCALEQ && gcol < 1024) ? 0.18033688011112042f : 1.0f;
#pragma unroll
      for (int r = 0; r < 4; ++r) {
        float v = (acc[i][j][r] + bv) * scl;
        size_t off = (size_t)(grow + r) * N + gcol;
        if (BF16OUT)
          ((bf16_t*)Cout)[off] = f2bf(v);
        else
          ((float*)Cout)[off] = v;
      }
    }
  }
}

// ---------------- fused causal attention (R22-verified; parked) ----------------
__global__ __launch_bounds__(256) void k_attn(const bf16_t* __restrict__ qkv,
                                              bf16_t* __restrict__ score) {
  __shared__ bf16_t Kl[2][64 * 64];
  __shared__ bf16_t Vt[2][64 * 64];
  __shared__ bf16_t Pl[4][16 * 64];
  const int tid = threadIdx.x;
  const int lane = tid & 63;
  const int w = tid >> 6;
  const int lr = lane & 15, lk = lane >> 4;

  const int flat = blockIdx.x;
  const int g = flat >> 5;
  const int idx = g & 7;
  const int grp = g >> 3;
  const int qt = (grp == 0) ? (31 - idx)
               : (grp == 1) ? (15 - idx)
               : (grp == 2) ? (16 + idx)
                            : idx;
  const int bh = flat & 31;
  const int b = bh >> 4, h = bh & 15;

  const bf16_t* Qb = qkv + (size_t)b * 2048 * 3072 + h * 64;
  const bf16_t* Kb = Qb + 1024;
  const bf16_t* Vb = Qb + 2048;

  int d0c[2], kv2[2], krow[2], kchk[2];
#pragma unroll
  for (int p = 0; p < 2; ++p) {
    int e = p * 256 + tid;
    d0c[p] = (e & 15) * 4;
    kv2[p] = (e >> 4) * 2;
    krow[p] = e >> 3;
    kchk[p] = (e & 7) ^ (krow[p] & 7);
  }

  const int qr0 = qt * 64 + w * 16;
  const int q = qr0 + lr;
  const int jtEnd = qt + 1;

  bf16x8 qf[2];
#pragma unroll
  for (int ks = 0; ks < 2; ++ks)
    qf[ks] = *(const bf16x8*)(Qb + (size_t)(qr0 + lr) * 3072 + ks * 32 + lk * 8);

  f32x4 o[4] = {};
  float l = 0.f;

  {
    bf16x4 v0[2][2];
#pragma unroll
    for (int p = 0; p < 2; ++p) {
      v0[p][0] = *(const bf16x4*)(Vb + (size_t)kv2[p] * 3072 + d0c[p]);
      v0[p][1] = *(const bf16x4*)(Vb + (size_t)(kv2[p] + 1) * 3072 + d0c[p]);
    }
#pragma unroll
    for (int p = 0; p < 2; ++p)
#pragma unroll
      for (int j = 0; j < 4; ++j) {
        int d = d0c[p] + j;
        int addr = (d * 128 + kv2[p] * 2) ^ (((d & 7) ^ ((d >> 3) & 7)) << 4);
        *(unsigned*)((char*)Vt + addr) = pack2(v0[p][0][j], v0[p][1][j]);
      }
  }
  bf16x4 vrA[2][2], vrB[2][2];
#pragma unroll
  for (int p = 0; p < 2; ++p) {
    vrA[p][0] = *(const bf16x4*)(Vb + (size_t)(64 + kv2[p]) * 3072 + d0c[p]);
    vrA[p][1] = *(const bf16x4*)(Vb + (size_t)(64 + kv2[p] + 1) * 3072 + d0c[p]);
  }
#pragma unroll
  for (int p = 0; p < 2; ++p)
    gld_lds16((const char*)Kb + ((size_t)krow[p] * 3072 + kchk[p] * 8) * 2,
              (char*)Kl + (p * 256 + tid) * 16);

  auto STEP = [&](int jt, bf16x4 (&vrC)[2][2], bf16x4 (&vrN)[2][2], bool last) {
    const int kv0 = jt * 64;
    asm volatile("s_waitcnt lgkmcnt(0)" ::: "memory");
    __builtin_amdgcn_s_barrier();
    char* wbase = (char*)Vt + (((jt + 1) & 1) << 13);
#pragma unroll
    for (int p = 0; p < 2; ++p)
#pragma unroll
      for (int j = 0; j < 4; ++j) {
        int d = d0c[p] + j;
        int addr = (d * 128 + kv2[p] * 2) ^ (((d & 7) ^ ((d >> 3) & 7)) << 4);
        *(unsigned*)(wbase + addr) = pack2(vrC[p][0][j], vrC[p][1][j]);
      }
    if (!last) {
      const int kvV = (kv0 + 128 < 2048) ? kv0 + 128 : 1920;
#pragma unroll
      for (int p = 0; p < 2; ++p) {
        vrN[p][0] = *(const bf16x4*)(Vb + (size_t)(kvV + kv2[p]) * 3072 + d0c[p]);
        vrN[p][1] = *(const bf16x4*)(Vb + (size_t)(kvV + kv2[p] + 1) * 3072 + d0c[p]);
      }
      char* kbase = (char*)Kl + (((jt + 1) & 1) << 13);
#pragma unroll
      for (int p = 0; p < 2; ++p)
        gld_lds16((const char*)Kb + ((size_t)(kv0 + 64 + krow[p]) * 3072 + kchk[p] * 8) * 2,
                  kbase + (p * 256 + tid) * 16);
      asm volatile("s_waitcnt vmcnt(6)" ::: "memory");
    } else {
      asm volatile("s_waitcnt vmcnt(0)" ::: "memory");
    }
    const char* kread = (const char*)Kl + ((jt & 1) << 13);
    bf16x8 kf[4][2];
#pragma unroll
    for (int nc = 0; nc < 4; ++nc) {
      const char* rowp = kread + (nc * 16 + lr) * 128;
      kf[nc][0] = *(const bf16x8*)(rowp + ((lk ^ (lr & 7)) << 4));
      kf[nc][1] = *(const bf16x8*)(rowp + (((4 | lk) ^ (lr & 7)) << 4));
    }
    f32x4 s[4];
    __builtin_amdgcn_s_setprio(1);
#pragma unroll
    for (int nc = 0; nc < 4; ++nc) {
      f32x4 z = {};
      z = MFMA16(kf[nc][0], qf[0], z);
      z = MFMA16(kf[nc][1], qf[1], z);
      s[nc] = z;
    }
    __builtin_amdgcn_s_setprio(0);
    if (kv0 + 63 > qr0) {
#pragma unroll
      for (int nc = 0; nc < 4; ++nc)
#pragma unroll
        for (int r = 0; r < 4; ++r) {
          int kvi = kv0 + nc * 16 + lk * 4 + r;
          if (kvi > q) s[nc][r] = -INFINITY;
        }
    }
#pragma unroll
    for (int nc = 0; nc < 4; ++nc)
#pragma unroll
      for (int r = 0; r < 4; ++r) {
        float p = exp2f(s[nc][r]);
        s[nc][r] = p;
        l += p;
      }
    bf16_t* Pw = Pl[w];
#pragma unroll
    for (int nc = 0; nc < 4; ++nc) {
      uint2 u;
      u.x = cvt_pk_bf16(s[nc][0], s[nc][1]);
      u.y = cvt_pk_bf16(s[nc][2], s[nc][3]);
      int addr = (lr * 128 + (nc * 16 + lk * 4) * 2) ^ ((lr & 7) << 4);
      *(uint2*)((char*)Pw + addr) = u;
    }
    const char* rbase = (const char*)Vt + ((jt & 1) << 13);
    bf16x8 pa[2];
#pragma unroll
    for (int ks = 0; ks < 2; ++ks) {
      int addr = (lr * 128 + ks * 64 + lk * 16) ^ ((lr & 7) << 4);
      pa[ks] = *(const bf16x8*)((const char*)Pl[w] + addr);
    }
    __builtin_amdgcn_s_setprio(1);
#pragma unroll
    for (int db = 0; db < 4; ++db)
#pragma unroll
      for (int ks = 0; ks < 2; ++ks) {
        int d = db * 16 + lr;
        int addr = (d * 128 + ks * 64 + lk * 16) ^ (((d & 7) ^ ((d >> 3) & 7)) << 4);
        bf16x8 vb = *(const bf16x8*)(rbase + addr);
        o[db] = MFMA16(vb, pa[ks], o[db]);
      }
    __builtin_amdgcn_s_setprio(0);
  };

  int jt = 0;
  for (;;) {
    STEP(jt, vrA, vrB, jt + 1 == jtEnd);
    if (++jt == jtEnd) break;
    STEP(jt, vrB, vrA, jt + 1 == jtEnd);
    if (++jt == jtEnd) break;
  }

  l += __shfl_xor(l, 16);
  l += __shfl_xor(l, 32);
  const float rl = 1.0f / l;
  bf16_t* orow = score + (size_t)(b * 2048 + q) * 1024 + h * 64 + lk * 4;
#pragma unroll
  for (int db = 0; db < 4; ++db) {
    unsigned w0 = cvt_pk_bf16(o[db][0] * rl, o[db][1] * rl);
    unsigned w1 = cvt_pk_bf16(o[db][2] * rl, o[db][3] * rl);
    uint2 pkt; pkt.x = w0; pkt.y = w1;
    *(uint2*)(orow + db * 16) = pkt;
  }
}

extern "C" void kernel_launch(void* const* d_in, const int* in_sizes, int n_in,
                              void* d_out, int out_size, void* d_ws, size_t ws_size,
                              hipStream_t stream) {
  const float* X  = (const float*)d_in[0];  // [2,2048,1024]
  const float* Wa = (const float*)d_in[1];  // [1024,3072]
  const float* ba = (const float*)d_in[2];  // [3072]
  const float* Wp = (const float*)d_in[3];  // [1024,1024]
  const float* bp = (const float*)d_in[4];  // [1024]
  float* out = (float*)d_out;               // [2,2048,1024] fp32

  char* ws = (char*)d_ws;
  bf16_t* Xb  = (bf16_t*)ws;                          // 8 MiB (reused as score)
  bf16_t* WaT = (bf16_t*)(ws + (size_t)(8u << 20));   // 6 MiB: W_attn^T [3072][1024]
  bf16_t* WpT = (bf16_t*)(ws + (size_t)(14u << 20));  // 2 MiB: W_proj^T [1024][1024]
  bf16_t* QKV = (bf16_t*)(ws + (size_t)(16u << 20));  // 24 MiB: [4096][3072]
  bf16_t* S_  = Xb;

  k_prep<<<3072, 256, 0, stream>>>(X, Xb, Wa, WaT, Wp, WpT);
  // QKV: BK=64, 128x128, 512T, 768 blocks (R23-verified)
  k_gemm64<true, true, 128, 128, 512><<<768, 512, 0, stream>>>(Xb, WaT, ba, QKV, 4096, 3072, 1024, 24);
  k_attn<<<1024, 256, 0, stream>>>(QKV, S_);
  // proj: BK=64, 64x64, 256T, 1024 blocks (R24: half the barrier events)
  k_gemm64<false, false, 64, 64, 256><<<1024, 256, 0, stream>>>(S_, WpT, bp, out, 4096, 1024, 1024, 16);
}